// Round 2
// baseline (154.222 us; speedup 1.0000x reference)
//
#include <hip/hip_runtime.h>
#include <math.h>

#define NJ  16
#define BLK 256

// Assumes nb % BLK == 0 (B = 262144 here). Block-cooperative writeout needs
// full blocks.
__global__ __launch_bounds__(BLK, 3) void poe_fwd(
    const float* __restrict__ q,        // B x 16
    const float* __restrict__ twist,    // 16 x 6 (uniform)
    const float* __restrict__ init_p,   // 3
    const float* __restrict__ init_rpy, // 3
    float* __restrict__ outT,           // B x 16
    float* __restrict__ outTw,          // B x 96
    int nb)
{
    // 128 rows x (24+1 pad) float4 = 50 KiB. Pad breaks the 96-float
    // (=3x32 banks) row-stride degeneracy: dword addr = 100*t + 4*k4 ->
    // bank group 4*((t+k4) mod 8) spreads 64 lanes over all 32 banks.
    __shared__ float4 lds4[128 * 25];

    const int tid = threadIdx.x;
    const int b   = blockIdx.x * BLK + tid;

    // ---- load 16 joint angles, vectorized ----
    float qv[NJ];
    {
        const float4* q4 = reinterpret_cast<const float4*>(q + (size_t)b * NJ);
        #pragma unroll
        for (int i = 0; i < NJ / 4; ++i) {
            float4 t = q4[i];
            qv[4*i+0] = t.x; qv[4*i+1] = t.y; qv[4*i+2] = t.z; qv[4*i+3] = t.w;
        }
    }

    // ---- running pose T = (R | p), bottom row implicit ----
    float R00=1.f, R01=0.f, R02=0.f;
    float R10=0.f, R11=1.f, R12=0.f;
    float R20=0.f, R21=0.f, R22=1.f;
    float p0=0.f, p1=0.f, p2=0.f;

    // Twistls accumulated in registers (all indices compile-time constant
    // under the unrolled loop -> stays in VGPRs, no scratch).
    float tw[NJ * 6];

    #pragma unroll
    for (int j = 0; j < NJ; ++j) {
        const float w0 = twist[j*6+0], w1 = twist[j*6+1], w2 = twist[j*6+2];
        const float v0 = twist[j*6+3], v1 = twist[j*6+4], v2 = twist[j*6+5];

        // tw_local with CURRENT pose: wl = R^T w ; vl = R^T (v - p x w)
        float u0 = v0 - (p1*w2 - p2*w1);
        float u1 = v1 - (p2*w0 - p0*w2);
        float u2 = v2 - (p0*w1 - p1*w0);
        tw[j*6+0] = R00*w0 + R10*w1 + R20*w2;
        tw[j*6+1] = R01*w0 + R11*w1 + R21*w2;
        tw[j*6+2] = R02*w0 + R12*w1 + R22*w2;
        tw[j*6+3] = R00*u0 + R10*u1 + R20*u2;
        tw[j*6+4] = R01*u0 + R11*u1 + R21*u2;
        tw[j*6+5] = R02*u0 + R12*u1 + R22*u2;

        // joint exponential A_j
        float ww    = w0*w0 + w1*w1 + w2*w2;
        float theta = sqrtf(ww) + 1e-12f;
        float inv   = 1.0f / theta;
        float wn0 = w0*inv, wn1 = w1*inv, wn2 = w2*inv;
        float vn0 = v0*inv, vn1 = v1*inv, vn2 = v2*inv;
        float qt  = qv[j] * theta;
        float s, cth;
        sincosf(qt, &s, &cth);
        float c  = 1.0f - cth;
        float ts = qt - s;

        float a00 = cth + c*wn0*wn0;
        float a01 = c*wn0*wn1 - s*wn2;
        float a02 = c*wn0*wn2 + s*wn1;
        float a10 = c*wn1*wn0 + s*wn2;
        float a11 = cth + c*wn1*wn1;
        float a12 = c*wn1*wn2 - s*wn0;
        float a20 = c*wn2*wn0 - s*wn1;
        float a21 = c*wn2*wn1 + s*wn0;
        float a22 = cth + c*wn2*wn2;

        float cx0 = wn1*vn2 - wn2*vn1;
        float cx1 = wn2*vn0 - wn0*vn2;
        float cx2 = wn0*vn1 - wn1*vn0;
        float d   = wn0*vn0 + wn1*vn1 + wn2*vn2;
        float td  = ts * d;
        float pj0 = s*vn0 + c*cx0 + td*wn0;
        float pj1 = s*vn1 + c*cx1 + td*wn1;
        float pj2 = s*vn2 + c*cx2 + td*wn2;

        // T = T @ A_j
        float n00 = R00*a00 + R01*a10 + R02*a20;
        float n01 = R00*a01 + R01*a11 + R02*a21;
        float n02 = R00*a02 + R01*a12 + R02*a22;
        float n10 = R10*a00 + R11*a10 + R12*a20;
        float n11 = R10*a01 + R11*a11 + R12*a21;
        float n12 = R10*a02 + R11*a12 + R12*a22;
        float n20 = R20*a00 + R21*a10 + R22*a20;
        float n21 = R20*a01 + R21*a11 + R22*a21;
        float n22 = R20*a02 + R21*a12 + R22*a22;
        float np0 = R00*pj0 + R01*pj1 + R02*pj2 + p0;
        float np1 = R10*pj0 + R11*pj1 + R12*pj2 + p1;
        float np2 = R20*pj0 + R21*pj1 + R22*pj2 + p2;
        R00=n00; R01=n01; R02=n02;
        R10=n10; R11=n11; R12=n12;
        R20=n20; R21=n21; R22=n22;
        p0=np0; p1=np1; p2=np2;
    }

    // ---- T_init = pr2t(init_p, init_rpy); final = T @ T_init ----
    float rr = init_rpy[0], pt = init_rpy[1], yw = init_rpy[2];
    float sr, cr, sp, cp, sy, cy;
    sincosf(rr, &sr, &cr);
    sincosf(pt, &sp, &cp);
    sincosf(yw, &sy, &cy);
    float i00 = cy*cp, i01 = cy*sp*sr - sy*cr, i02 = cy*sp*cr + sy*sr;
    float i10 = sy*cp, i11 = sy*sp*sr + cy*cr, i12 = sy*sp*cr - cy*sr;
    float i20 = -sp,   i21 = cp*sr,            i22 = cp*cr;
    float ip0 = init_p[0], ip1 = init_p[1], ip2 = init_p[2];

    float f00 = R00*i00 + R01*i10 + R02*i20;
    float f01 = R00*i01 + R01*i11 + R02*i21;
    float f02 = R00*i02 + R01*i12 + R02*i22;
    float f10 = R10*i00 + R11*i10 + R12*i20;
    float f11 = R10*i01 + R11*i11 + R12*i21;
    float f12 = R10*i02 + R11*i12 + R12*i22;
    float f20 = R20*i00 + R21*i10 + R22*i20;
    float f21 = R20*i01 + R21*i11 + R22*i21;
    float f22 = R20*i02 + R21*i12 + R22*i22;
    float fp0 = R00*ip0 + R01*ip1 + R02*ip2 + p0;
    float fp1 = R10*ip0 + R11*ip1 + R12*ip2 + p1;
    float fp2 = R20*ip0 + R21*ip1 + R22*ip2 + p2;

    // ==== coalesced Twistls writeout: two half-block phases through LDS ====
    // Block's Twistls region: 256 threads x 24 float4 = 6144 float4, contiguous.
    float4* outTw4 = reinterpret_cast<float4*>(outTw) + (size_t)blockIdx.x * (BLK * 24);

    #pragma unroll
    for (int ph = 0; ph < 2; ++ph) {
        __syncthreads();
        if ((tid >> 7) == ph) {
            int t = tid & 127;
            #pragma unroll
            for (int k4 = 0; k4 < 24; ++k4)
                lds4[t * 25 + k4] =
                    make_float4(tw[4*k4+0], tw[4*k4+1], tw[4*k4+2], tw[4*k4+3]);
        }
        __syncthreads();
        // 128 threads' worth = 3072 float4 = 48 KiB, fully contiguous.
        #pragma unroll
        for (int i = 0; i < 12; ++i) {
            int f4 = i * BLK + tid;
            int t  = f4 / 24;            // magic-mul division
            int k4 = f4 - t * 24;
            outTw4[ph * 3072 + f4] = lds4[t * 25 + k4];
        }
    }

    // ==== coalesced outT writeout via LDS (16 KiB contiguous per block) ====
    __syncthreads();
    lds4[tid * 5 + 0] = make_float4(f00, f01, f02, fp0);
    lds4[tid * 5 + 1] = make_float4(f10, f11, f12, fp1);
    lds4[tid * 5 + 2] = make_float4(f20, f21, f22, fp2);
    lds4[tid * 5 + 3] = make_float4(0.f, 0.f, 0.f, 1.f);
    __syncthreads();
    float4* outT4 = reinterpret_cast<float4*>(outT) + (size_t)blockIdx.x * (BLK * 4);
    #pragma unroll
    for (int i = 0; i < 4; ++i) {
        int f4 = i * BLK + tid;
        int t  = f4 >> 2;
        int c  = f4 & 3;
        outT4[f4] = lds4[t * 5 + c];
    }
}

extern "C" void kernel_launch(void* const* d_in, const int* in_sizes, int n_in,
                              void* d_out, int out_size, void* d_ws, size_t ws_size,
                              hipStream_t stream) {
    const float* q        = (const float*)d_in[0];
    const float* twist    = (const float*)d_in[1];
    const float* init_p   = (const float*)d_in[2];
    const float* init_rpy = (const float*)d_in[3];

    int nb = in_sizes[0] / NJ;   // B (divisible by 256 for this problem)
    float* outT  = (float*)d_out;                  // B x 16 (4x4 matrices)
    float* outTw = outT + (size_t)nb * 16;         // B x 96 (Twistls)

    int blocks = nb / BLK;
    poe_fwd<<<blocks, BLK, 0, stream>>>(q, twist, init_p, init_rpy, outT, outTw, nb);
}

// Round 3
// 49.999 us; speedup vs baseline: 3.0845x; 3.0845x over previous
//
#include <hip/hip_runtime.h>
#include <math.h>

#define NJ  16
#define BLK 256

__global__ __launch_bounds__(BLK) void poe_fwd(
    const float* __restrict__ q,        // B x 16
    const float* __restrict__ twist,    // 16 x 6 (uniform)
    const float* __restrict__ init_p,   // 3
    const float* __restrict__ init_rpy, // 3
    float* __restrict__ outT,           // B x 16
    float* __restrict__ outTw,          // B x 96
    int nb)
{
    int b = blockIdx.x * BLK + threadIdx.x;
    if (b >= nb) return;

    // ---- load 16 joint angles, vectorized ----
    float qv[NJ];
    {
        const float4* q4 = reinterpret_cast<const float4*>(q + (size_t)b * NJ);
        #pragma unroll
        for (int i = 0; i < NJ / 4; ++i) {
            float4 t = q4[i];
            qv[4*i+0] = t.x; qv[4*i+1] = t.y; qv[4*i+2] = t.z; qv[4*i+3] = t.w;
        }
    }

    // ---- running pose T = (R | p), bottom row implicit ----
    float R00=1.f, R01=0.f, R02=0.f;
    float R10=0.f, R11=1.f, R12=0.f;
    float R20=0.f, R21=0.f, R22=1.f;
    float p0=0.f, p1=0.f, p2=0.f;

    // Half-slot buffer: 8 joints x 6 floats = 48 floats = 12 float4 = 192 B
    // = exactly 3 whole 64-B lines per flush (slot is 384-B aligned).
    // Small enough to stay in VGPRs (no launch_bounds cap this time).
    float hb[48];

    float4* twb4 = reinterpret_cast<float4*>(outTw + (size_t)b * (NJ * 6));

    #pragma unroll
    for (int j = 0; j < NJ; ++j) {
        const float w0 = twist[j*6+0], w1 = twist[j*6+1], w2 = twist[j*6+2];
        const float v0 = twist[j*6+3], v1 = twist[j*6+4], v2 = twist[j*6+5];

        // tw_local with CURRENT pose: wl = R^T w ; vl = R^T (v - p x w)
        float u0 = v0 - (p1*w2 - p2*w1);
        float u1 = v1 - (p2*w0 - p0*w2);
        float u2 = v2 - (p0*w1 - p1*w0);
        const int o = (j & 7) * 6;           // compile-time under unroll
        hb[o+0] = R00*w0 + R10*w1 + R20*w2;
        hb[o+1] = R01*w0 + R11*w1 + R21*w2;
        hb[o+2] = R02*w0 + R12*w1 + R22*w2;
        hb[o+3] = R00*u0 + R10*u1 + R20*u2;
        hb[o+4] = R01*u0 + R11*u1 + R21*u2;
        hb[o+5] = R02*u0 + R12*u1 + R22*u2;

        // joint exponential A_j
        float ww    = w0*w0 + w1*w1 + w2*w2;
        float theta = sqrtf(ww) + 1e-12f;
        float inv   = 1.0f / theta;
        float wn0 = w0*inv, wn1 = w1*inv, wn2 = w2*inv;
        float vn0 = v0*inv, vn1 = v1*inv, vn2 = v2*inv;
        float qt  = qv[j] * theta;
        float s, cth;
        sincosf(qt, &s, &cth);
        float c  = 1.0f - cth;
        float ts = qt - s;

        float a00 = cth + c*wn0*wn0;
        float a01 = c*wn0*wn1 - s*wn2;
        float a02 = c*wn0*wn2 + s*wn1;
        float a10 = c*wn1*wn0 + s*wn2;
        float a11 = cth + c*wn1*wn1;
        float a12 = c*wn1*wn2 - s*wn0;
        float a20 = c*wn2*wn0 - s*wn1;
        float a21 = c*wn2*wn1 + s*wn0;
        float a22 = cth + c*wn2*wn2;

        float cx0 = wn1*vn2 - wn2*vn1;
        float cx1 = wn2*vn0 - wn0*vn2;
        float cx2 = wn0*vn1 - wn1*vn0;
        float d   = wn0*vn0 + wn1*vn1 + wn2*vn2;
        float td  = ts * d;
        float pj0 = s*vn0 + c*cx0 + td*wn0;
        float pj1 = s*vn1 + c*cx1 + td*wn1;
        float pj2 = s*vn2 + c*cx2 + td*wn2;

        // T = T @ A_j
        float n00 = R00*a00 + R01*a10 + R02*a20;
        float n01 = R00*a01 + R01*a11 + R02*a21;
        float n02 = R00*a02 + R01*a12 + R02*a22;
        float n10 = R10*a00 + R11*a10 + R12*a20;
        float n11 = R10*a01 + R11*a11 + R12*a21;
        float n12 = R10*a02 + R11*a12 + R12*a22;
        float n20 = R20*a00 + R21*a10 + R22*a20;
        float n21 = R20*a01 + R21*a11 + R22*a21;
        float n22 = R20*a02 + R21*a12 + R22*a22;
        float np0 = R00*pj0 + R01*pj1 + R02*pj2 + p0;
        float np1 = R10*pj0 + R11*pj1 + R12*pj2 + p1;
        float np2 = R20*pj0 + R21*pj1 + R22*pj2 + p2;
        R00=n00; R01=n01; R02=n02;
        R10=n10; R11=n11; R12=n12;
        R20=n20; R21=n21; R22=n22;
        p0=np0; p1=np1; p2=np2;

        // ---- flush half-slot as 12 back-to-back float4 stores ----
        if ((j & 7) == 7) {
            const int base = (j >> 3) * 12;  // 0 or 12 (float4 units)
            #pragma unroll
            for (int k = 0; k < 12; ++k)
                twb4[base + k] =
                    make_float4(hb[4*k+0], hb[4*k+1], hb[4*k+2], hb[4*k+3]);
        }
    }

    // ---- T_init = pr2t(init_p, init_rpy); final = T @ T_init ----
    float rr = init_rpy[0], pt = init_rpy[1], yw = init_rpy[2];
    float sr, cr, sp, cp, sy, cy;
    sincosf(rr, &sr, &cr);
    sincosf(pt, &sp, &cp);
    sincosf(yw, &sy, &cy);
    float i00 = cy*cp, i01 = cy*sp*sr - sy*cr, i02 = cy*sp*cr + sy*sr;
    float i10 = sy*cp, i11 = sy*sp*sr + cy*cr, i12 = sy*sp*cr - cy*sr;
    float i20 = -sp,   i21 = cp*sr,            i22 = cp*cr;
    float ip0 = init_p[0], ip1 = init_p[1], ip2 = init_p[2];

    float f00 = R00*i00 + R01*i10 + R02*i20;
    float f01 = R00*i01 + R01*i11 + R02*i21;
    float f02 = R00*i02 + R01*i12 + R02*i22;
    float f10 = R10*i00 + R11*i10 + R12*i20;
    float f11 = R10*i01 + R11*i11 + R12*i21;
    float f12 = R10*i02 + R11*i12 + R12*i22;
    float f20 = R20*i00 + R21*i10 + R22*i20;
    float f21 = R20*i01 + R21*i11 + R22*i21;
    float f22 = R20*i02 + R21*i12 + R22*i22;
    float fp0 = R00*ip0 + R01*ip1 + R02*ip2 + p0;
    float fp1 = R10*ip0 + R11*ip1 + R12*ip2 + p1;
    float fp2 = R20*ip0 + R21*ip1 + R22*ip2 + p2;

    // outT: 64 B contiguous per thread = one full line, 4 back-to-back stores.
    float4* o4 = reinterpret_cast<float4*>(outT + (size_t)b * 16);
    o4[0] = make_float4(f00, f01, f02, fp0);
    o4[1] = make_float4(f10, f11, f12, fp1);
    o4[2] = make_float4(f20, f21, f22, fp2);
    o4[3] = make_float4(0.f, 0.f, 0.f, 1.f);
}

extern "C" void kernel_launch(void* const* d_in, const int* in_sizes, int n_in,
                              void* d_out, int out_size, void* d_ws, size_t ws_size,
                              hipStream_t stream) {
    const float* q        = (const float*)d_in[0];
    const float* twist    = (const float*)d_in[1];
    const float* init_p   = (const float*)d_in[2];
    const float* init_rpy = (const float*)d_in[3];

    int nb = in_sizes[0] / NJ;   // B
    float* outT  = (float*)d_out;                  // B x 16 (4x4 matrices)
    float* outTw = outT + (size_t)nb * 16;         // B x 96 (Twistls)

    int blocks = (nb + BLK - 1) / BLK;
    poe_fwd<<<blocks, BLK, 0, stream>>>(q, twist, init_p, init_rpy, outT, outTw, nb);
}

// Round 4
// 49.445 us; speedup vs baseline: 3.1191x; 1.0112x over previous
//
#include <hip/hip_runtime.h>
#include <math.h>

#define NJ    16
#define BLK   256
#define WAVES (BLK / 64)

// Requires nb % BLK == 0 (B = 262144 -> 1024 blocks). Wave-cooperative
// writeout: all LDS traffic is intra-wave64, no barriers needed.
__global__ __launch_bounds__(BLK) void poe_fwd(
    const float* __restrict__ q,        // B x 16
    const float* __restrict__ twist,    // 16 x 6 (uniform)
    const float* __restrict__ init_p,   // 3
    const float* __restrict__ init_rpy, // 3
    float* __restrict__ outT,           // B x 16
    float* __restrict__ outTw,          // B x 96
    int nb)
{
    // Per-wave staging: 64 rows x (12+1 pad) float4. Row stride 13 float4
    // (52 dwords): 52*t mod 32 walks disjoint 4-bank quads over 8-lane
    // groups -> conflict-free b128 writes. 4 waves * 13312 B = 53 KiB.
    __shared__ float4 lds4[WAVES * 64 * 13];

    const int tid  = threadIdx.x;
    const int lane = tid & 63;
    const int wid  = tid >> 6;
    float4* wbuf = &lds4[wid * (64 * 13)];

    const int b = blockIdx.x * BLK + tid;

    // ---- load 16 joint angles, vectorized ----
    float qv[NJ];
    {
        const float4* q4 = reinterpret_cast<const float4*>(q + (size_t)b * NJ);
        #pragma unroll
        for (int i = 0; i < NJ / 4; ++i) {
            float4 t = q4[i];
            qv[4*i+0] = t.x; qv[4*i+1] = t.y; qv[4*i+2] = t.z; qv[4*i+3] = t.w;
        }
    }

    // ---- running pose T = (R | p), bottom row implicit ----
    float R00=1.f, R01=0.f, R02=0.f;
    float R10=0.f, R11=1.f, R12=0.f;
    float R20=0.f, R21=0.f, R22=1.f;
    float p0=0.f, p1=0.f, p2=0.f;

    // Half-slot register buffer: 8 joints x 6 = 48 floats (static indexing
    // under full unroll -> VGPRs; no launch-bounds cap so no spill).
    float hb[48];

    // Wave's 64 elements start at (blockIdx*BLK + wid*64); slot = 24 float4.
    float4* twdst = reinterpret_cast<float4*>(outTw) +
                    (size_t)(blockIdx.x * BLK + wid * 64) * 24;

    #pragma unroll
    for (int j = 0; j < NJ; ++j) {
        const float w0 = twist[j*6+0], w1 = twist[j*6+1], w2 = twist[j*6+2];
        const float v0 = twist[j*6+3], v1 = twist[j*6+4], v2 = twist[j*6+5];

        // tw_local with CURRENT pose: wl = R^T w ; vl = R^T (v - p x w)
        float u0 = v0 - (p1*w2 - p2*w1);
        float u1 = v1 - (p2*w0 - p0*w2);
        float u2 = v2 - (p0*w1 - p1*w0);
        const int o = (j & 7) * 6;           // compile-time under unroll
        hb[o+0] = R00*w0 + R10*w1 + R20*w2;
        hb[o+1] = R01*w0 + R11*w1 + R21*w2;
        hb[o+2] = R02*w0 + R12*w1 + R22*w2;
        hb[o+3] = R00*u0 + R10*u1 + R20*u2;
        hb[o+4] = R01*u0 + R11*u1 + R21*u2;
        hb[o+5] = R02*u0 + R12*u1 + R22*u2;

        // joint exponential A_j
        float ww    = w0*w0 + w1*w1 + w2*w2;
        float theta = sqrtf(ww) + 1e-12f;
        float inv   = 1.0f / theta;
        float wn0 = w0*inv, wn1 = w1*inv, wn2 = w2*inv;
        float vn0 = v0*inv, vn1 = v1*inv, vn2 = v2*inv;
        float qt  = qv[j] * theta;
        float s, cth;
        sincosf(qt, &s, &cth);
        float c  = 1.0f - cth;
        float ts = qt - s;

        float a00 = cth + c*wn0*wn0;
        float a01 = c*wn0*wn1 - s*wn2;
        float a02 = c*wn0*wn2 + s*wn1;
        float a10 = c*wn1*wn0 + s*wn2;
        float a11 = cth + c*wn1*wn1;
        float a12 = c*wn1*wn2 - s*wn0;
        float a20 = c*wn2*wn0 - s*wn1;
        float a21 = c*wn2*wn1 + s*wn0;
        float a22 = cth + c*wn2*wn2;

        float cx0 = wn1*vn2 - wn2*vn1;
        float cx1 = wn2*vn0 - wn0*vn2;
        float cx2 = wn0*vn1 - wn1*vn0;
        float d   = wn0*vn0 + wn1*vn1 + wn2*vn2;
        float td  = ts * d;
        float pj0 = s*vn0 + c*cx0 + td*wn0;
        float pj1 = s*vn1 + c*cx1 + td*wn1;
        float pj2 = s*vn2 + c*cx2 + td*wn2;

        // T = T @ A_j
        float n00 = R00*a00 + R01*a10 + R02*a20;
        float n01 = R00*a01 + R01*a11 + R02*a21;
        float n02 = R00*a02 + R01*a12 + R02*a22;
        float n10 = R10*a00 + R11*a10 + R12*a20;
        float n11 = R10*a01 + R11*a11 + R12*a21;
        float n12 = R10*a02 + R11*a12 + R12*a22;
        float n20 = R20*a00 + R21*a10 + R22*a20;
        float n21 = R20*a01 + R21*a11 + R22*a21;
        float n22 = R20*a02 + R21*a12 + R22*a22;
        float np0 = R00*pj0 + R01*pj1 + R02*pj2 + p0;
        float np1 = R10*pj0 + R11*pj1 + R12*pj2 + p1;
        float np2 = R20*pj0 + R21*pj1 + R22*pj2 + p2;
        R00=n00; R01=n01; R02=n02;
        R10=n10; R11=n11; R12=n12;
        R20=n20; R21=n21; R22=n22;
        p0=np0; p1=np1; p2=np2;

        // ---- half-slot flush: wave-level LDS transpose + segment-optimal
        //      stores. Each store inst covers 16 whole 64-B segments
        //      (g = i*64+lane in address order; 64 mod 12 = 4 keeps every
        //      inst on 4-float4 line-quad boundaries). ----
        if ((j & 7) == 7) {
            #pragma unroll
            for (int k = 0; k < 12; ++k)
                wbuf[lane * 13 + k] =
                    make_float4(hb[4*k+0], hb[4*k+1], hb[4*k+2], hb[4*k+3]);
            const int h = j >> 3;            // 0 or 1
            #pragma unroll
            for (int i = 0; i < 12; ++i) {
                int g  = i * 64 + lane;      // piece index within wave's half set
                int r  = g / 12;             // source element (row)
                int k4 = g - r * 12;         // float4 within half-slot
                twdst[r * 24 + h * 12 + k4] = wbuf[r * 13 + k4];
            }
        }
    }

    // ---- T_init = pr2t(init_p, init_rpy); final = T @ T_init ----
    float rr = init_rpy[0], pt = init_rpy[1], yw = init_rpy[2];
    float sr, cr, sp, cp, sy, cy;
    sincosf(rr, &sr, &cr);
    sincosf(pt, &sp, &cp);
    sincosf(yw, &sy, &cy);
    float i00 = cy*cp, i01 = cy*sp*sr - sy*cr, i02 = cy*sp*cr + sy*sr;
    float i10 = sy*cp, i11 = sy*sp*sr + cy*cr, i12 = sy*sp*cr - cy*sr;
    float i20 = -sp,   i21 = cp*sr,            i22 = cp*cr;
    float ip0 = init_p[0], ip1 = init_p[1], ip2 = init_p[2];

    float f00 = R00*i00 + R01*i10 + R02*i20;
    float f01 = R00*i01 + R01*i11 + R02*i21;
    float f02 = R00*i02 + R01*i12 + R02*i22;
    float f10 = R10*i00 + R11*i10 + R12*i20;
    float f11 = R10*i01 + R11*i11 + R12*i21;
    float f12 = R10*i02 + R11*i12 + R12*i22;
    float f20 = R20*i00 + R21*i10 + R22*i20;
    float f21 = R20*i01 + R21*i11 + R22*i21;
    float f22 = R20*i02 + R21*i12 + R22*i22;
    float fp0 = R00*ip0 + R01*ip1 + R02*ip2 + p0;
    float fp1 = R10*ip0 + R11*ip1 + R12*ip2 + p1;
    float fp2 = R20*ip0 + R21*ip1 + R22*ip2 + p2;

    // ---- outT: wave transpose -> 4 KiB contiguous, 16 segments/inst ----
    wbuf[lane * 13 + 0] = make_float4(f00, f01, f02, fp0);
    wbuf[lane * 13 + 1] = make_float4(f10, f11, f12, fp1);
    wbuf[lane * 13 + 2] = make_float4(f20, f21, f22, fp2);
    wbuf[lane * 13 + 3] = make_float4(0.f, 0.f, 0.f, 1.f);
    float4* tdst = reinterpret_cast<float4*>(outT) +
                   (size_t)(blockIdx.x * BLK + wid * 64) * 4;
    #pragma unroll
    for (int i = 0; i < 4; ++i) {
        int g  = i * 64 + lane;
        int r  = g >> 2;
        int k4 = g & 3;
        tdst[g] = wbuf[r * 13 + k4];
    }
}

extern "C" void kernel_launch(void* const* d_in, const int* in_sizes, int n_in,
                              void* d_out, int out_size, void* d_ws, size_t ws_size,
                              hipStream_t stream) {
    const float* q        = (const float*)d_in[0];
    const float* twist    = (const float*)d_in[1];
    const float* init_p   = (const float*)d_in[2];
    const float* init_rpy = (const float*)d_in[3];

    int nb = in_sizes[0] / NJ;   // B (divisible by 256 here)
    float* outT  = (float*)d_out;                  // B x 16 (4x4 matrices)
    float* outTw = outT + (size_t)nb * 16;         // B x 96 (Twistls)

    int blocks = nb / BLK;
    poe_fwd<<<blocks, BLK, 0, stream>>>(q, twist, init_p, init_rpy, outT, outTw, nb);
}

// Round 5
// 47.421 us; speedup vs baseline: 3.2522x; 1.0427x over previous
//
#include <hip/hip_runtime.h>
#include <math.h>

#define NJ  16
#define BLK 256

// Affine 3x4: m[0..8] = row-major R, m[9..11] = p.
struct Mat { float m[12]; };

// C = A @ B (apply B, then A) — matches T_new = T_old @ A_j ordering when
// called as mul(earlier, later).
__device__ __forceinline__ Mat mul(const Mat& A, const Mat& B) {
    Mat C;
    #pragma unroll
    for (int r = 0; r < 3; ++r) {
        float a0 = A.m[3*r+0], a1 = A.m[3*r+1], a2 = A.m[3*r+2];
        C.m[3*r+0] = a0*B.m[0] + a1*B.m[3] + a2*B.m[6];
        C.m[3*r+1] = a0*B.m[1] + a1*B.m[4] + a2*B.m[7];
        C.m[3*r+2] = a0*B.m[2] + a1*B.m[5] + a2*B.m[8];
        C.m[9+r]   = a0*B.m[9] + a1*B.m[10] + a2*B.m[11] + A.m[9+r];
    }
    return C;
}

// srodrigues for one joint: tw6 = (w0..w2, v0..v2), angle qj.
__device__ __forceinline__ Mat buildA(const float* tw6, float qj) {
    float w0 = tw6[0], w1 = tw6[1], w2 = tw6[2];
    float v0 = tw6[3], v1 = tw6[4], v2 = tw6[5];
    float theta = sqrtf(w0*w0 + w1*w1 + w2*w2) + 1e-12f;
    float inv   = __builtin_amdgcn_rcpf(theta);
    float wn0 = w0*inv, wn1 = w1*inv, wn2 = w2*inv;
    float vn0 = v0*inv, vn1 = v1*inv, vn2 = v2*inv;
    float qt  = qj * theta;
    float s   = __sinf(qt);
    float cth = __cosf(qt);
    float c   = 1.0f - cth;
    float ts  = qt - s;
    Mat A;
    A.m[0] = cth + c*wn0*wn0;  A.m[1] = c*wn0*wn1 - s*wn2; A.m[2] = c*wn0*wn2 + s*wn1;
    A.m[3] = c*wn1*wn0 + s*wn2; A.m[4] = cth + c*wn1*wn1;  A.m[5] = c*wn1*wn2 - s*wn0;
    A.m[6] = c*wn2*wn0 - s*wn1; A.m[7] = c*wn2*wn1 + s*wn0; A.m[8] = cth + c*wn2*wn2;
    float cx0 = wn1*vn2 - wn2*vn1;
    float cx1 = wn2*vn0 - wn0*vn2;
    float cx2 = wn0*vn1 - wn1*vn0;
    float d   = wn0*vn0 + wn1*vn1 + wn2*vn2;
    float td  = ts * d;
    A.m[9]  = s*vn0 + c*cx0 + td*wn0;
    A.m[10] = s*vn1 + c*cx1 + td*wn1;
    A.m[11] = s*vn2 + c*cx2 + td*wn2;
    return A;
}

// 4 lanes per batch element; lane handles 4 consecutive joints.
// Chain product via 2-step Kogge-Stone scan of affine matrices within quads.
__global__ __launch_bounds__(BLK) void poe_fwd(
    const float* __restrict__ q,        // B x 16
    const float* __restrict__ twist,    // 16 x 6 (uniform)
    const float* __restrict__ init_p,   // 3
    const float* __restrict__ init_rpy, // 3
    float* __restrict__ outT,           // B x 16
    float* __restrict__ outTw,          // B x 96
    int nb)
{
    const int g    = blockIdx.x * BLK + threadIdx.x;   // global lane
    const int e    = g >> 2;                           // batch element
    const int s    = g & 3;                            // segment id (joints 4s..4s+3)
    const int lane = threadIdx.x & 63;
    if (e >= nb) return;

    // q for my 4 joints: one float4, fully coalesced across the wave.
    float qk[4];
    {
        float4 t = reinterpret_cast<const float4*>(q)[(size_t)e * 4 + s];
        qk[0] = t.x; qk[1] = t.y; qk[2] = t.z; qk[3] = t.w;
    }

    // twist rows 4s..4s+3 (24 floats, 96 B, L1-resident broadcast).
    float tws[24];
    {
        const float4* t4 = reinterpret_cast<const float4*>(twist) + s * 6;
        #pragma unroll
        for (int i = 0; i < 6; ++i) {
            float4 t = t4[i];
            tws[4*i+0] = t.x; tws[4*i+1] = t.y; tws[4*i+2] = t.z; tws[4*i+3] = t.w;
        }
    }

    // ---- phase 1: serial product of my segment: B_s = A_{4s}..A_{4s+3} ----
    Mat P = buildA(&tws[0], qk[0]);
    #pragma unroll
    for (int k = 1; k < 4; ++k)
        P = mul(P, buildA(&tws[6*k], qk[k]));

    // ---- inclusive scan over the quad (Kogge-Stone, steps 1,2) ----
    #pragma unroll
    for (int step = 1; step < 4; step <<= 1) {
        const bool use = (s >= step);
        const int  src = use ? lane - step : lane;
        Mat T;
        #pragma unroll
        for (int i = 0; i < 12; ++i) T.m[i] = __shfl(P.m[i], src, 64);
        Mat M = mul(T, P);
        #pragma unroll
        for (int i = 0; i < 12; ++i) P.m[i] = use ? M.m[i] : P.m[i];
    }
    // lane s now holds prefix through joint 4s+3; lane 3 = full 16-joint chain.

    // ---- exclusive prefix = entry pose for my segment ----
    Mat pose;
    {
        const int src = (s == 0) ? lane : lane - 1;
        #pragma unroll
        for (int i = 0; i < 12; ++i) pose.m[i] = __shfl(P.m[i], src, 64);
        const float id[12] = {1,0,0, 0,1,0, 0,0,1, 0,0,0};
        #pragma unroll
        for (int i = 0; i < 12; ++i) pose.m[i] = (s == 0) ? id[i] : pose.m[i];
    }

    // ---- phase 2: replay my 4 joints for tw_local; store 24 B per joint ----
    float2* twb = reinterpret_cast<float2*>(outTw) + (size_t)g * 12;
    #pragma unroll
    for (int k = 0; k < 4; ++k) {
        const float* t6 = &tws[6*k];
        float w0 = t6[0], w1 = t6[1], w2 = t6[2];
        float v0 = t6[3], v1 = t6[4], v2 = t6[5];
        float p0 = pose.m[9], p1 = pose.m[10], p2 = pose.m[11];
        float u0 = v0 - (p1*w2 - p2*w1);
        float u1 = v1 - (p2*w0 - p0*w2);
        float u2 = v2 - (p0*w1 - p1*w0);
        float wl0 = pose.m[0]*w0 + pose.m[3]*w1 + pose.m[6]*w2;
        float wl1 = pose.m[1]*w0 + pose.m[4]*w1 + pose.m[7]*w2;
        float wl2 = pose.m[2]*w0 + pose.m[5]*w1 + pose.m[8]*w2;
        float vl0 = pose.m[0]*u0 + pose.m[3]*u1 + pose.m[6]*u2;
        float vl1 = pose.m[1]*u0 + pose.m[4]*u1 + pose.m[7]*u2;
        float vl2 = pose.m[2]*u0 + pose.m[5]*u1 + pose.m[8]*u2;
        twb[3*k+0] = make_float2(wl0, wl1);
        twb[3*k+1] = make_float2(wl2, vl0);
        twb[3*k+2] = make_float2(vl1, vl2);
        if (k < 3)  // pose after k=3 is P (already held); skip dead multiply
            pose = mul(pose, buildA(t6, qk[k]));
    }

    // ---- final: fetch full-chain product from quad lane 3, apply T_init ----
    Mat F;
    {
        const int src = lane | 3;
        #pragma unroll
        for (int i = 0; i < 12; ++i) F.m[i] = __shfl(P.m[i], src, 64);
    }
    float rr = init_rpy[0], pt = init_rpy[1], yw = init_rpy[2];
    float sr = __sinf(rr), cr = __cosf(rr);
    float sp = __sinf(pt), cp = __cosf(pt);
    float sy = __sinf(yw), cy = __cosf(yw);
    float i00 = cy*cp, i01 = cy*sp*sr - sy*cr, i02 = cy*sp*cr + sy*sr;
    float i10 = sy*cp, i11 = sy*sp*sr + cy*cr, i12 = sy*sp*cr - cy*sr;
    float i20 = -sp,   i21 = cp*sr,            i22 = cp*cr;
    float ip0 = init_p[0], ip1 = init_p[1], ip2 = init_p[2];

    // my output row = s (row 3 is constant 0001)
    float r0 = (s == 0) ? F.m[0] : (s == 1) ? F.m[3] : F.m[6];
    float r1 = (s == 0) ? F.m[1] : (s == 1) ? F.m[4] : F.m[7];
    float r2 = (s == 0) ? F.m[2] : (s == 1) ? F.m[5] : F.m[8];
    float pr = (s == 0) ? F.m[9] : (s == 1) ? F.m[10] : F.m[11];
    float4 row;
    row.x = r0*i00 + r1*i10 + r2*i20;
    row.y = r0*i01 + r1*i11 + r2*i21;
    row.z = r0*i02 + r1*i12 + r2*i22;
    row.w = r0*ip0 + r1*ip1 + r2*ip2 + pr;
    if (s == 3) row = make_float4(0.f, 0.f, 0.f, 1.f);

    // one float4 per lane, fully contiguous across the wave (1 KiB/inst).
    reinterpret_cast<float4*>(outT)[(size_t)g] = row;
}

extern "C" void kernel_launch(void* const* d_in, const int* in_sizes, int n_in,
                              void* d_out, int out_size, void* d_ws, size_t ws_size,
                              hipStream_t stream) {
    const float* q        = (const float*)d_in[0];
    const float* twist    = (const float*)d_in[1];
    const float* init_p   = (const float*)d_in[2];
    const float* init_rpy = (const float*)d_in[3];

    int nb = in_sizes[0] / NJ;   // B
    float* outT  = (float*)d_out;                  // B x 16 (4x4 matrices)
    float* outTw = outT + (size_t)nb * 16;         // B x 96 (Twistls)

    int threads = nb * 4;                          // 4 lanes per element
    int blocks  = (threads + BLK - 1) / BLK;
    poe_fwd<<<blocks, BLK, 0, stream>>>(q, twist, init_p, init_rpy, outT, outTw, nb);
}